// Round 8
// baseline (258.179 us; speedup 1.0000x reference)
//
#include <hip/hip_runtime.h>
#include <hip/hip_bf16.h>

#define BB 8
#define LL 200
#define HH 128
#define NHEAD 4
#define HDIM 32
#define NBLK 2
#define BL (BB * LL)
#define NT 257            // TIME_SPAN+1
#define QT 8              // queries per attention tile
#define NQT 25            // 200/8
#define SSP 208           // attn score row stride
#define KC 132            // attn KstT row stride (>=129, /4)
#define ASP 36            // qkv A-tile stride [k][m]
#define BSP 66            // B-tile stride [k][j], j<64
#define FSP 132           // ffn row stride

static constexpr float SQRT_H    = 11.313708498984761f;   // sqrt(128)
static constexpr float INV_SCALE = 0.17677669529663687f;  // 1/sqrt(32)
static constexpr float PADV      = -4294967295.0f;        // -2^32+1

// ===== QKV GEMM: [1600x128] @ [128x384], 50 Mtiles x 6 Ntiles ==============
__global__ void k_qkv_gemm(const float* __restrict__ seqs_in,
                           const int* __restrict__ log_seqs,
                           const float* __restrict__ item_emb,
                           const float* __restrict__ g, const float* __restrict__ bia,
                           const float* __restrict__ Wq, const float* __restrict__ bq,
                           const float* __restrict__ Wk, const float* __restrict__ bk,
                           const float* __restrict__ Wv, const float* __restrict__ bv,
                           const float* __restrict__ posK, const float* __restrict__ posV,
                           float* __restrict__ Qin, float* __restrict__ Q,
                           float* __restrict__ K, float* __restrict__ V) {
    int mt = blockIdx.x / 6, nt = blockIdx.x % 6;
    int matsel = nt >> 1;              // 0=Q 1=K 2=V
    int jb = (nt & 1) * 64;
    int row0 = mt * 32;
    int tid = threadIdx.x;
    __shared__ float As[128 * ASP];
    __shared__ float Bs[128 * BSP];

    {   // stage A: 32 rows x 128, 8 threads/row; LN for Q-tiles
        int r = tid >> 3, seg = tid & 7;
        int row = row0 + r;
        float4 vv[4];
        if (seqs_in) {
            #pragma unroll
            for (int i = 0; i < 4; i++)
                vv[i] = *(const float4*)(seqs_in + (size_t)row * HH + seg * 16 + i * 4);
        } else {
            int idx = log_seqs[row];
            if (idx == 0) {
                #pragma unroll
                for (int i = 0; i < 4; i++) vv[i] = make_float4(0.f, 0.f, 0.f, 0.f);
            } else {
                #pragma unroll
                for (int i = 0; i < 4; i++) {
                    float4 e = *(const float4*)(item_emb + (size_t)idx * HH + seg * 16 + i * 4);
                    vv[i] = make_float4(e.x * SQRT_H, e.y * SQRT_H, e.z * SQRT_H, e.w * SQRT_H);
                }
            }
        }
        if (matsel == 0) {
            float s = 0.f, s2 = 0.f;
            #pragma unroll
            for (int i = 0; i < 4; i++) {
                s  += vv[i].x + vv[i].y + vv[i].z + vv[i].w;
                s2 += vv[i].x * vv[i].x + vv[i].y * vv[i].y + vv[i].z * vv[i].z + vv[i].w * vv[i].w;
            }
            #pragma unroll
            for (int off = 1; off < 8; off <<= 1) {
                s  += __shfl_xor(s, off);
                s2 += __shfl_xor(s2, off);
            }
            float mean = s * (1.f / HH);
            float var  = s2 * (1.f / HH) - mean * mean;
            float inv  = 1.f / sqrtf(var + 1e-8f);
            #pragma unroll
            for (int i = 0; i < 4; i++) {
                int k = seg * 16 + i * 4;
                float4 g4 = *(const float4*)(g + k);
                float4 b4 = *(const float4*)(bia + k);
                float4 y;
                y.x = (vv[i].x - mean) * inv * g4.x + b4.x;
                y.y = (vv[i].y - mean) * inv * g4.y + b4.y;
                y.z = (vv[i].z - mean) * inv * g4.z + b4.z;
                y.w = (vv[i].w - mean) * inv * g4.w + b4.w;
                As[(k + 0) * ASP + r] = y.x;
                As[(k + 1) * ASP + r] = y.y;
                As[(k + 2) * ASP + r] = y.z;
                As[(k + 3) * ASP + r] = y.w;
                if (nt == 0) *(float4*)(Qin + (size_t)row * HH + k) = y;
            }
        } else {
            #pragma unroll
            for (int i = 0; i < 4; i++) {
                int k = seg * 16 + i * 4;
                As[(k + 0) * ASP + r] = vv[i].x;
                As[(k + 1) * ASP + r] = vv[i].y;
                As[(k + 2) * ASP + r] = vv[i].z;
                As[(k + 3) * ASP + r] = vv[i].w;
            }
        }
    }
    {   // stage B
        const float* W = (matsel == 0) ? Wq : (matsel == 1) ? Wk : Wv;
        int k4 = tid & 31, jj0 = tid >> 5;
        #pragma unroll
        for (int p = 0; p < 8; p++) {
            int jj = jj0 + p * 8;
            float4 w = *(const float4*)(W + (size_t)(jb + jj) * HH + k4 * 4);
            Bs[(k4 * 4 + 0) * BSP + jj] = w.x;
            Bs[(k4 * 4 + 1) * BSP + jj] = w.y;
            Bs[(k4 * 4 + 2) * BSP + jj] = w.z;
            Bs[(k4 * 4 + 3) * BSP + jj] = w.w;
        }
    }
    __syncthreads();

    int my = tid >> 5, jx = tid & 31;
    float a00=0,a01=0,a10=0,a11=0,a20=0,a21=0,a30=0,a31=0;
    #pragma unroll 4
    for (int k = 0; k < HH; k++) {
        float4 a = *(const float4*)&As[k * ASP + my * 4];
        float2 b = *(const float2*)&Bs[k * BSP + jx * 2];
        a00 += a.x * b.x; a01 += a.x * b.y;
        a10 += a.y * b.x; a11 += a.y * b.y;
        a20 += a.z * b.x; a21 += a.z * b.y;
        a30 += a.w * b.x; a31 += a.w * b.y;
    }
    float accs[4][2] = {{a00,a01},{a10,a11},{a20,a21},{a30,a31}};
    int col = jb + jx * 2;
    if (matsel == 0) {
        float2 bb = *(const float2*)(bq + col);
        #pragma unroll
        for (int r = 0; r < 4; r++) {
            int row = row0 + my * 4 + r;
            float2 o = make_float2((accs[r][0] + bb.x) * INV_SCALE,
                                   (accs[r][1] + bb.y) * INV_SCALE);
            *(float2*)(Q + (size_t)row * HH + col) = o;
        }
    } else if (matsel == 1) {
        float2 bb = *(const float2*)(bk + col);
        #pragma unroll
        for (int r = 0; r < 4; r++) {
            int row = row0 + my * 4 + r;
            int l = row % LL;
            float2 pk = *(const float2*)(posK + (size_t)l * HH + col);
            *(float2*)(K + (size_t)row * HH + col) =
                make_float2(accs[r][0] + bb.x + pk.x, accs[r][1] + bb.y + pk.y);
        }
    } else {
        float2 bb = *(const float2*)(bv + col);
        #pragma unroll
        for (int r = 0; r < 4; r++) {
            int row = row0 + my * 4 + r;
            int l = row % LL;
            float2 pv = *(const float2*)(posV + (size_t)l * HH + col);
            *(float2*)(V + (size_t)row * HH + col) =
                make_float2(accs[r][0] + bb.x + pv.x, accs[r][1] + bb.y + pv.y);
        }
    }
}

// ===== attention v4: block = (b, head, 8-q tile), 256 threads ==============
// DT table for K-side scores; E-phase gathers timeV directly (d-coalesced);
// no W-binning, no LDS atomics in softmax.
__global__ void k_attn(const float* __restrict__ Q, const float* __restrict__ K,
                       const float* __restrict__ V,
                       const float* __restrict__ timeK, const float* __restrict__ timeV,
                       const int* __restrict__ tm,
                       float* __restrict__ att) {
    int bn = blockIdx.x & 31;
    int b = bn >> 2, n = bn & 3;
    int qt = (NQT - 1) - (blockIdx.x >> 5);   // heavy tiles first
    int q0 = qt * QT;
    int kmax = q0 + QT - 1;                   // <= 199 always
    int tid = threadIdx.x;
    int wv = tid >> 6, ln = tid & 63;

    __shared__ float Qs[QT * HDIM];           // 1 KB
    __shared__ float KstT[HDIM * KC];         // 16.9 KB
    __shared__ float DTW[QT * NT];            // 8.2 KB
    __shared__ float Ssc[QT * SSP];           // 6.7 KB
    __shared__ unsigned short tmst[QT * LL];  // 3.2 KB
    __shared__ float Ost[QT * HDIM];          // 1 KB

    Ost[tid] = 0.f;
    if (tid < 64) {
        int qi = tid >> 3, d4 = tid & 7;
        *(float4*)(Qs + qi * HDIM + d4 * 4) =
            *(const float4*)(Q + ((size_t)(b * LL + q0 + qi)) * HH + n * HDIM + d4 * 4);
    }
    for (int idx = tid; idx < QT * LL; idx += 256) {
        int qi = idx / LL, k = idx - qi * LL;
        tmst[idx] = (unsigned short)tm[((size_t)(b * LL + q0 + qi)) * LL + k];
    }
    __syncthreads();

    int qi_c = tid >> 5, k2 = tid & 31;

    // ---- B: DT[qi][tau] = Qh . timeKh[tau]; chunks {0..127},{128..256} ----
    for (int c = 0; c < 2; c++) {
        int base = c * 128, rows = c ? 129 : 128;
        #pragma unroll
        for (int p = 0; p < 5; p++) {
            int idx = tid + p * 256;
            int r = idx >> 3, d4 = idx & 7;
            if (r < rows) {
                float4 w = *(const float4*)(timeK + (size_t)(base + r) * HH + n * HDIM + d4 * 4);
                KstT[(d4 * 4 + 0) * KC + r] = w.x;
                KstT[(d4 * 4 + 1) * KC + r] = w.y;
                KstT[(d4 * 4 + 2) * KC + r] = w.z;
                KstT[(d4 * 4 + 3) * KC + r] = w.w;
            }
        }
        __syncthreads();
        float a0 = 0, a1 = 0, a2 = 0, a3 = 0;
        int col = k2 * 4;
        #pragma unroll 8
        for (int d = 0; d < HDIM; d++) {
            float qv = Qs[qi_c * HDIM + d];
            float4 kv = *(const float4*)&KstT[d * KC + col];
            a0 += qv * kv.x; a1 += qv * kv.y; a2 += qv * kv.z; a3 += qv * kv.w;
        }
        float* dt = &DTW[qi_c * NT + base + col];
        dt[0] = a0; dt[1] = a1; dt[2] = a2; dt[3] = a3;
        if (c == 1 && k2 == 0) {   // tau = 256 (staged col 128)
            float a = 0.f;
            #pragma unroll 8
            for (int d = 0; d < HDIM; d++) a += Qs[qi_c * HDIM + d] * KstT[d * KC + 128];
            DTW[qi_c * NT + 256] = a;
        }
        __syncthreads();
    }

    // ---- C: S[qi][k] = Qh.Kh[k] + DT[qi][tm[k]] (k <= q only) ----
    int nch = (kmax >> 7) + 1;
    for (int c = 0; c < nch; c++) {
        int base = c * 128;
        int rows = min(128, kmax + 1 - base);
        #pragma unroll
        for (int p = 0; p < 4; p++) {
            int idx = tid + p * 256;
            int r = idx >> 3, d4 = idx & 7;
            if (r < rows) {
                float4 w = *(const float4*)(K + ((size_t)(b * LL + base + r)) * HH + n * HDIM + d4 * 4);
                KstT[(d4 * 4 + 0) * KC + r] = w.x;
                KstT[(d4 * 4 + 1) * KC + r] = w.y;
                KstT[(d4 * 4 + 2) * KC + r] = w.z;
                KstT[(d4 * 4 + 3) * KC + r] = w.w;
            }
        }
        __syncthreads();
        float av[4] = {0, 0, 0, 0};
        int col = k2 * 4;
        #pragma unroll 8
        for (int d = 0; d < HDIM; d++) {
            float qv = Qs[qi_c * HDIM + d];
            float4 kv = *(const float4*)&KstT[d * KC + col];
            av[0] += qv * kv.x; av[1] += qv * kv.y; av[2] += qv * kv.z; av[3] += qv * kv.w;
        }
        int q = q0 + qi_c;
        #pragma unroll
        for (int j = 0; j < 4; j++) {
            int k = base + col + j;
            if (k <= q)
                Ssc[qi_c * SSP + k] = av[j] + DTW[qi_c * NT + tmst[qi_c * LL + k]];
        }
        __syncthreads();
    }

    // ---- D: softmax per q-row (wave wv -> rows wv, wv+4) ----
    for (int rr = 0; rr < 2; rr++) {
        int qi = wv + rr * 4;
        int q = q0 + qi;
        float sv[4];
        float m = -3.0e38f;
        #pragma unroll
        for (int jj = 0; jj < 4; jj++) {
            int k = ln + 64 * jj;
            sv[jj] = (k <= q) ? Ssc[qi * SSP + k] : -3.0e38f;
            m = fmaxf(m, sv[jj]);
        }
        for (int off = 32; off; off >>= 1) m = fmaxf(m, __shfl_xor(m, off));
        float sum = 0.f;
        #pragma unroll
        for (int jj = 0; jj < 4; jj++) {
            int k = ln + 64 * jj;
            sv[jj] = (k <= q) ? __expf(sv[jj] - m) : 0.f;
            sum += sv[jj];
        }
        for (int off = 32; off; off >>= 1) sum += __shfl_xor(sum, off);
        float inv = 1.f / sum;
        #pragma unroll
        for (int jj = 0; jj < 4; jj++) {
            int k = ln + 64 * jj;
            if (k <= q) Ssc[qi * SSP + k] = sv[jj] * inv;
        }
    }
    __syncthreads();

    // ---- E: O[qi][d] = sum_k p * (V[k][d] + timeV[t[qi][k]][d]) ----
    int d = tid & 31, kg = tid >> 5;
    float acc[QT] = {0,0,0,0,0,0,0,0};
    const float* vb  = V + ((size_t)(b * LL)) * HH + n * HDIM + d;
    const float* tvb = timeV + n * HDIM + d;
    for (int k = kg; k <= kmax; k += 8) {
        float v = vb[(size_t)k * HH];
        #pragma unroll
        for (int qi = 0; qi < QT; qi++) {
            if (q0 + qi >= k) {
                float tv = tvb[(size_t)tmst[qi * LL + k] * HH];
                acc[qi] += Ssc[qi * SSP + k] * (v + tv);
            }
        }
    }
    #pragma unroll
    for (int qi = 0; qi < QT; qi++) {
        acc[qi] += __shfl_xor(acc[qi], 32);
        if ((kg & 1) == 0) atomicAdd(&Ost[qi * HDIM + d], acc[qi]);
    }
    __syncthreads();
    {
        int qi = tid >> 5;
        att[((size_t)(b * LL + q0 + qi)) * HH + n * HDIM + (tid & 31)] = Ost[tid];
    }
}

// ===== fused FFN (+last-LN+logits): M=4 rows, N=128, 256 threads ===========
__global__ void k_ffn(const float* __restrict__ Qin, const float* __restrict__ att,
                      const float* __restrict__ g, const float* __restrict__ bia,
                      const float* __restrict__ W1, const float* __restrict__ b1,
                      const float* __restrict__ W2, const float* __restrict__ b2,
                      const int* __restrict__ log_seqs,
                      const float* __restrict__ lg, const float* __restrict__ lb,
                      const float* __restrict__ item_emb,
                      const int* __restrict__ pos, const int* __restrict__ neg,
                      float* __restrict__ out, float* __restrict__ logits, int last) {
    int row0 = blockIdx.x * 4;
    int tid = threadIdx.x;
    int wv = tid >> 6, ln = tid & 63;
    __shared__ float As[4 * FSP];     // y = LN(Qin+att), later out
    __shared__ float H1[4 * FSP];
    __shared__ float Bs[128 * BSP];   // 64-col W chunk, transposed

    {   // A: per-row LN (wave wv owns row wv)
        int row = row0 + wv;
        float v0 = Qin[(size_t)row * HH + ln]      + att[(size_t)row * HH + ln];
        float v1 = Qin[(size_t)row * HH + ln + 64] + att[(size_t)row * HH + ln + 64];
        float s = v0 + v1, s2 = v0 * v0 + v1 * v1;
        for (int off = 32; off; off >>= 1) {
            s  += __shfl_xor(s, off);
            s2 += __shfl_xor(s2, off);
        }
        float mean = s * (1.f / HH);
        float var  = s2 * (1.f / HH) - mean * mean;
        float inv  = 1.f / sqrtf(var + 1e-8f);
        As[wv * FSP + ln]      = (v0 - mean) * inv * g[ln]      + bia[ln];
        As[wv * FSP + ln + 64] = (v1 - mean) * inv * g[ln + 64] + bia[ln + 64];
    }
    __syncthreads();

    int jx = ln;   // col within chunk
    // ---- FF1: h1 = relu(y @ W1^T + b1) ----
    for (int c = 0; c < 2; c++) {
        int k4 = tid & 31, jj0 = tid >> 5;
        #pragma unroll
        for (int p = 0; p < 8; p++) {
            int jj = jj0 + p * 8;
            float4 w = *(const float4*)(W1 + (size_t)(c * 64 + jj) * HH + k4 * 4);
            Bs[(k4 * 4 + 0) * BSP + jj] = w.x;
            Bs[(k4 * 4 + 1) * BSP + jj] = w.y;
            Bs[(k4 * 4 + 2) * BSP + jj] = w.z;
            Bs[(k4 * 4 + 3) * BSP + jj] = w.w;
        }
        __syncthreads();
        float acc = 0.f;
        #pragma unroll 8
        for (int k = 0; k < HH; k++)
            acc += As[wv * FSP + k] * Bs[k * BSP + jx];
        int col = c * 64 + jx;
        float t = acc + b1[col];
        H1[wv * FSP + col] = t > 0.f ? t : 0.f;
        __syncthreads();
    }

    // ---- FF2: o = h1 @ W2^T + b2 + y, keep ----
    int rowm = row0 + wv;
    int keepz = (log_seqs[rowm] == 0);
    for (int c = 0; c < 2; c++) {
        int k4 = tid & 31, jj0 = tid >> 5;
        #pragma unroll
        for (int p = 0; p < 8; p++) {
            int jj = jj0 + p * 8;
            float4 w = *(const float4*)(W2 + (size_t)(c * 64 + jj) * HH + k4 * 4);
            Bs[(k4 * 4 + 0) * BSP + jj] = w.x;
            Bs[(k4 * 4 + 1) * BSP + jj] = w.y;
            Bs[(k4 * 4 + 2) * BSP + jj] = w.z;
            Bs[(k4 * 4 + 3) * BSP + jj] = w.w;
        }
        __syncthreads();
        float acc = 0.f;
        #pragma unroll 8
        for (int k = 0; k < HH; k++)
            acc += H1[wv * FSP + k] * Bs[k * BSP + jx];
        int col = c * 64 + jx;
        float o = acc + b2[col] + As[wv * FSP + col];
        if (keepz) o = 0.f;
        if (!last) out[(size_t)rowm * HH + col] = o;
        As[wv * FSP + col] = o;
        __syncthreads();
    }

    // ---- last layer: LN + pos/neg logits ----
    if (last) {
        float o0 = As[wv * FSP + ln], o1 = As[wv * FSP + ln + 64];
        float s = o0 + o1, s2 = o0 * o0 + o1 * o1;
        for (int off = 32; off; off >>= 1) {
            s  += __shfl_xor(s, off);
            s2 += __shfl_xor(s2, off);
        }
        float mean = s * (1.f / HH);
        float var  = s2 * (1.f / HH) - mean * mean;
        float inv  = 1.f / sqrtf(var + 1e-8f);
        float f0 = (o0 - mean) * inv * lg[ln]      + lb[ln];
        float f1 = (o1 - mean) * inv * lg[ln + 64] + lb[ln + 64];
        int ip = pos[rowm], in_ = neg[rowm];
        float vp = f0 * item_emb[(size_t)ip * HH + ln] + f1 * item_emb[(size_t)ip * HH + ln + 64];
        float vn = f0 * item_emb[(size_t)in_ * HH + ln] + f1 * item_emb[(size_t)in_ * HH + ln + 64];
        for (int off = 32; off; off >>= 1) {
            vp += __shfl_xor(vp, off);
            vn += __shfl_xor(vn, off);
        }
        if (ln == 0) {
            logits[rowm]      = vp;
            logits[BL + rowm] = vn;
        }
    }
}

extern "C" void kernel_launch(void* const* d_in, const int* in_sizes, int n_in,
                              void* d_out, int out_size, void* d_ws, size_t ws_size,
                              hipStream_t stream) {
    const int* log_seqs   = (const int*)d_in[1];
    const int* tm         = (const int*)d_in[2];
    const int* pos_seqs   = (const int*)d_in[3];
    const int* neg_seqs   = (const int*)d_in[4];
    const float* item_emb = (const float*)d_in[5];
    const float* posK     = (const float*)d_in[6];
    const float* posV     = (const float*)d_in[7];
    const float* timeK    = (const float*)d_in[8];
    const float* timeV    = (const float*)d_in[9];
    const float* attn_g   = (const float*)d_in[10];
    const float* attn_b   = (const float*)d_in[11];
    const float* Wq       = (const float*)d_in[12];
    const float* bq       = (const float*)d_in[13];
    const float* Wk       = (const float*)d_in[14];
    const float* bk       = (const float*)d_in[15];
    const float* Wv       = (const float*)d_in[16];
    const float* bv       = (const float*)d_in[17];
    const float* fwd_g    = (const float*)d_in[18];
    const float* fwd_b    = (const float*)d_in[19];
    const float* W1       = (const float*)d_in[20];
    const float* b1       = (const float*)d_in[21];
    const float* W2       = (const float*)d_in[22];
    const float* b2       = (const float*)d_in[23];
    const float* last_g   = (const float*)d_in[24];
    const float* last_b   = (const float*)d_in[25];

    float* seqs = (float*)d_ws;            // 6 x B*L*H f32 = ~4.9 MB
    float* Qin  = seqs + (size_t)BL * HH;
    float* Qb   = Qin  + (size_t)BL * HH;
    float* Kb   = Qb   + (size_t)BL * HH;
    float* Vb   = Kb   + (size_t)BL * HH;
    float* att  = Vb   + (size_t)BL * HH;

    for (int i = 0; i < NBLK; i++) {
        k_qkv_gemm<<<300, 256, 0, stream>>>(i == 0 ? nullptr : seqs, log_seqs, item_emb,
                                            attn_g + i * HH, attn_b + i * HH,
                                            Wq + (size_t)i * HH * HH, bq + i * HH,
                                            Wk + (size_t)i * HH * HH, bk + i * HH,
                                            Wv + (size_t)i * HH * HH, bv + i * HH,
                                            posK, posV, Qin, Qb, Kb, Vb);
        k_attn<<<NQT * 32, 256, 0, stream>>>(Qb, Kb, Vb, timeK, timeV, tm, att);
        k_ffn<<<BL / 4, 256, 0, stream>>>(Qin, att, fwd_g + i * HH, fwd_b + i * HH,
                                          W1 + (size_t)i * HH * HH, b1 + i * HH,
                                          W2 + (size_t)i * HH * HH, b2 + i * HH,
                                          log_seqs, last_g, last_b, item_emb,
                                          pos_seqs, neg_seqs,
                                          seqs, (float*)d_out, (i == NBLK - 1) ? 1 : 0);
    }
}

// Round 9
// 249.630 us; speedup vs baseline: 1.0342x; 1.0342x over previous
//
#include <hip/hip_runtime.h>
#include <hip/hip_bf16.h>

#define BB 8
#define LL 200
#define HH 128
#define NHEAD 4
#define HDIM 32
#define NBLK 2
#define BL (BB * LL)
#define NT 257            // TIME_SPAN+1
#define NQT4 50           // 200/4 q-tiles
#define SSP 208           // attn score row stride
#define KSP 36            // attn staging row stride (row-major, 144B = 9x16)
#define ASP 36            // qkv A-tile stride [k][m]
#define BSP 66            // B-tile stride [k][j], j<64
#define FSP 132           // ffn row stride

static constexpr float SQRT_H    = 11.313708498984761f;   // sqrt(128)
static constexpr float INV_SCALE = 0.17677669529663687f;  // 1/sqrt(32)

// ===== QKV GEMM: [1600x128] @ [128x384], 50 Mtiles x 6 Ntiles ==============
__global__ void k_qkv_gemm(const float* __restrict__ seqs_in,
                           const int* __restrict__ log_seqs,
                           const float* __restrict__ item_emb,
                           const float* __restrict__ g, const float* __restrict__ bia,
                           const float* __restrict__ Wq, const float* __restrict__ bq,
                           const float* __restrict__ Wk, const float* __restrict__ bk,
                           const float* __restrict__ Wv, const float* __restrict__ bv,
                           const float* __restrict__ posK, const float* __restrict__ posV,
                           float* __restrict__ Qin, float* __restrict__ Q,
                           float* __restrict__ K, float* __restrict__ V) {
    int mt = blockIdx.x / 6, nt = blockIdx.x % 6;
    int matsel = nt >> 1;              // 0=Q 1=K 2=V
    int jb = (nt & 1) * 64;
    int row0 = mt * 32;
    int tid = threadIdx.x;
    __shared__ float As[128 * ASP];
    __shared__ float Bs[128 * BSP];

    {   // stage A: 32 rows x 128, 8 threads/row; LN for Q-tiles
        int r = tid >> 3, seg = tid & 7;
        int row = row0 + r;
        float4 vv[4];
        if (seqs_in) {
            #pragma unroll
            for (int i = 0; i < 4; i++)
                vv[i] = *(const float4*)(seqs_in + (size_t)row * HH + seg * 16 + i * 4);
        } else {
            int idx = log_seqs[row];
            if (idx == 0) {
                #pragma unroll
                for (int i = 0; i < 4; i++) vv[i] = make_float4(0.f, 0.f, 0.f, 0.f);
            } else {
                #pragma unroll
                for (int i = 0; i < 4; i++) {
                    float4 e = *(const float4*)(item_emb + (size_t)idx * HH + seg * 16 + i * 4);
                    vv[i] = make_float4(e.x * SQRT_H, e.y * SQRT_H, e.z * SQRT_H, e.w * SQRT_H);
                }
            }
        }
        if (matsel == 0) {
            float s = 0.f, s2 = 0.f;
            #pragma unroll
            for (int i = 0; i < 4; i++) {
                s  += vv[i].x + vv[i].y + vv[i].z + vv[i].w;
                s2 += vv[i].x * vv[i].x + vv[i].y * vv[i].y + vv[i].z * vv[i].z + vv[i].w * vv[i].w;
            }
            #pragma unroll
            for (int off = 1; off < 8; off <<= 1) {
                s  += __shfl_xor(s, off);
                s2 += __shfl_xor(s2, off);
            }
            float mean = s * (1.f / HH);
            float var  = s2 * (1.f / HH) - mean * mean;
            float inv  = 1.f / sqrtf(var + 1e-8f);
            #pragma unroll
            for (int i = 0; i < 4; i++) {
                int k = seg * 16 + i * 4;
                float4 g4 = *(const float4*)(g + k);
                float4 b4 = *(const float4*)(bia + k);
                float4 y;
                y.x = (vv[i].x - mean) * inv * g4.x + b4.x;
                y.y = (vv[i].y - mean) * inv * g4.y + b4.y;
                y.z = (vv[i].z - mean) * inv * g4.z + b4.z;
                y.w = (vv[i].w - mean) * inv * g4.w + b4.w;
                As[(k + 0) * ASP + r] = y.x;
                As[(k + 1) * ASP + r] = y.y;
                As[(k + 2) * ASP + r] = y.z;
                As[(k + 3) * ASP + r] = y.w;
                if (nt == 0) *(float4*)(Qin + (size_t)row * HH + k) = y;
            }
        } else {
            #pragma unroll
            for (int i = 0; i < 4; i++) {
                int k = seg * 16 + i * 4;
                As[(k + 0) * ASP + r] = vv[i].x;
                As[(k + 1) * ASP + r] = vv[i].y;
                As[(k + 2) * ASP + r] = vv[i].z;
                As[(k + 3) * ASP + r] = vv[i].w;
            }
        }
    }
    {   // stage B
        const float* W = (matsel == 0) ? Wq : (matsel == 1) ? Wk : Wv;
        int k4 = tid & 31, jj0 = tid >> 5;
        #pragma unroll
        for (int p = 0; p < 8; p++) {
            int jj = jj0 + p * 8;
            float4 w = *(const float4*)(W + (size_t)(jb + jj) * HH + k4 * 4);
            Bs[(k4 * 4 + 0) * BSP + jj] = w.x;
            Bs[(k4 * 4 + 1) * BSP + jj] = w.y;
            Bs[(k4 * 4 + 2) * BSP + jj] = w.z;
            Bs[(k4 * 4 + 3) * BSP + jj] = w.w;
        }
    }
    __syncthreads();

    int my = tid >> 5, jx = tid & 31;
    float a00=0,a01=0,a10=0,a11=0,a20=0,a21=0,a30=0,a31=0;
    #pragma unroll 4
    for (int k = 0; k < HH; k++) {
        float4 a = *(const float4*)&As[k * ASP + my * 4];
        float2 b = *(const float2*)&Bs[k * BSP + jx * 2];
        a00 += a.x * b.x; a01 += a.x * b.y;
        a10 += a.y * b.x; a11 += a.y * b.y;
        a20 += a.z * b.x; a21 += a.z * b.y;
        a30 += a.w * b.x; a31 += a.w * b.y;
    }
    float accs[4][2] = {{a00,a01},{a10,a11},{a20,a21},{a30,a31}};
    int col = jb + jx * 2;
    if (matsel == 0) {
        float2 bb = *(const float2*)(bq + col);
        #pragma unroll
        for (int r = 0; r < 4; r++) {
            int row = row0 + my * 4 + r;
            *(float2*)(Q + (size_t)row * HH + col) =
                make_float2((accs[r][0] + bb.x) * INV_SCALE, (accs[r][1] + bb.y) * INV_SCALE);
        }
    } else if (matsel == 1) {
        float2 bb = *(const float2*)(bk + col);
        #pragma unroll
        for (int r = 0; r < 4; r++) {
            int row = row0 + my * 4 + r;
            int l = row % LL;
            float2 pk = *(const float2*)(posK + (size_t)l * HH + col);
            *(float2*)(K + (size_t)row * HH + col) =
                make_float2(accs[r][0] + bb.x + pk.x, accs[r][1] + bb.y + pk.y);
        }
    } else {
        float2 bb = *(const float2*)(bv + col);
        #pragma unroll
        for (int r = 0; r < 4; r++) {
            int row = row0 + my * 4 + r;
            int l = row % LL;
            float2 pv = *(const float2*)(posV + (size_t)l * HH + col);
            *(float2*)(V + (size_t)row * HH + col) =
                make_float2(accs[r][0] + bb.x + pv.x, accs[r][1] + bb.y + pv.y);
        }
    }
}

// ===== attention v5: block = (b, head, 4-q tile); wave = one q row =========
// Row-major staging (KSP=36: conflict-free b128); Q in regs; tau-binned E.
__global__ void k_attn(const float* __restrict__ Q, const float* __restrict__ K,
                       const float* __restrict__ V,
                       const float* __restrict__ timeK, const float* __restrict__ timeV,
                       const int* __restrict__ tm,
                       float* __restrict__ att) {
    int bn = blockIdx.x & 31;
    int b = bn >> 2, n = bn & 3;
    int qt = (NQT4 - 1) - (blockIdx.x >> 5);   // heavy tiles first
    int q0 = qt * 4;
    int kmax = q0 + 3;
    int tid = threadIdx.x;
    int wv = tid >> 6, ln = tid & 63;

    __shared__ float Kst[128 * KSP];     // 18.4 KB staging (rows x 32d)
    __shared__ float DTW[4 * NT];        // 4.1 KB  DT table
    __shared__ float WB[4 * NT];         // 4.1 KB  tau bins
    __shared__ float Ssc[4 * SSP];       // 3.3 KB  scores -> P
    __shared__ int   tmst[4 * LL];       // 3.2 KB
    __shared__ float Qs[4][HDIM];        // 0.5 KB
    __shared__ float Ost[4 * HDIM];      // 0.5 KB
    // ~34.2 KB -> 4 blocks/CU

    // ---- A: Qs, tmst, zero WB/Ost ----
    if (tid < 128) {
        int qi = tid >> 5, d = tid & 31;
        Qs[qi][d] = Q[((size_t)(b * LL + q0 + qi)) * HH + n * HDIM + d];
        Ost[tid] = 0.f;
    }
    for (int idx = tid; idx < 4 * NT; idx += 256) WB[idx] = 0.f;
    for (int idx = tid; idx < 4 * LL; idx += 256) {
        int qi = idx / LL, k = idx - qi * LL;
        tmst[idx] = tm[((size_t)(b * LL + q0 + qi)) * LL + k];
    }
    __syncthreads();

    float qreg[HDIM];
    #pragma unroll
    for (int d = 0; d < HDIM; d++) qreg[d] = Qs[wv][d];
    int q_my = q0 + wv;

    // ---- B: DT[wv][tau] = q . timeKh[tau], chunks {128, 129} ----
    for (int c = 0; c < 2; c++) {
        int base = c * 128;
        int rows = c ? (NT - 128) : 128;
        int tot = rows * 8;
        for (int idx = tid; idx < tot; idx += 256) {
            int r = idx >> 3, d4 = idx & 7;
            *(float4*)&Kst[r * KSP + d4 * 4] =
                *(const float4*)(timeK + (size_t)(base + r) * HH + n * HDIM + d4 * 4);
        }
        __syncthreads();
        #pragma unroll
        for (int j = 0; j < 3; j++) {
            int rl = ln + 64 * j;
            if (rl < rows) {
                float a = 0.f;
                #pragma unroll
                for (int d4 = 0; d4 < 8; d4++) {
                    float4 kk = *(const float4*)&Kst[rl * KSP + d4 * 4];
                    a += qreg[d4*4+0] * kk.x + qreg[d4*4+1] * kk.y
                       + qreg[d4*4+2] * kk.z + qreg[d4*4+3] * kk.w;
                }
                DTW[wv * NT + base + rl] = a;
            }
        }
        __syncthreads();
    }

    // ---- C: S[wv][k] = q.Kh[k] + DT[wv][tm[k]] (k <= q_my) ----
    int nch = (kmax >> 7) + 1;
    for (int c = 0; c < nch; c++) {
        int base = c * 128;
        int rows = min(128, kmax + 1 - base);
        int tot = rows * 8;
        for (int idx = tid; idx < tot; idx += 256) {
            int r = idx >> 3, d4 = idx & 7;
            *(float4*)&Kst[r * KSP + d4 * 4] =
                *(const float4*)(K + ((size_t)(b * LL + base + r)) * HH + n * HDIM + d4 * 4);
        }
        __syncthreads();
        #pragma unroll
        for (int j = 0; j < 2; j++) {
            int rl = ln + 64 * j;
            int k = base + rl;
            if (rl < rows && k <= q_my) {
                float a = 0.f;
                #pragma unroll
                for (int d4 = 0; d4 < 8; d4++) {
                    float4 kk = *(const float4*)&Kst[rl * KSP + d4 * 4];
                    a += qreg[d4*4+0] * kk.x + qreg[d4*4+1] * kk.y
                       + qreg[d4*4+2] * kk.z + qreg[d4*4+3] * kk.w;
                }
                Ssc[wv * SSP + k] = a + DTW[wv * NT + tmst[wv * LL + k]];
            }
        }
        __syncthreads();
    }

    // ---- D: per-wave softmax on own q-row + scatter bins ----
    {
        float sv[4];
        float m = -3.0e38f;
        #pragma unroll
        for (int j = 0; j < 4; j++) {
            int k = ln + 64 * j;
            sv[j] = (k <= q_my) ? Ssc[wv * SSP + k] : -3.0e38f;
            m = fmaxf(m, sv[j]);
        }
        for (int off = 32; off; off >>= 1) m = fmaxf(m, __shfl_xor(m, off));
        float sum = 0.f;
        #pragma unroll
        for (int j = 0; j < 4; j++) {
            int k = ln + 64 * j;
            sv[j] = (k <= q_my) ? __expf(sv[j] - m) : 0.f;
            sum += sv[j];
        }
        for (int off = 32; off; off >>= 1) sum += __shfl_xor(sum, off);
        float inv = 1.f / sum;
        #pragma unroll
        for (int j = 0; j < 4; j++) {
            int k = ln + 64 * j;
            float p = sv[j] * inv;
            if (k < SSP) Ssc[wv * SSP + k] = (k <= q_my) ? p : 0.f;
            if (k <= q_my) atomicAdd(&WB[wv * NT + tmst[wv * LL + k]], p);
        }
    }
    __syncthreads();

    // ---- E: O = P@Vh + W@timeVh (thread = (d, k-group)) ----
    int d = tid & 31, kg = tid >> 5;   // kg 0..7
    float a0 = 0.f, a1 = 0.f, a2 = 0.f, a3 = 0.f;
    const float* vb = V + ((size_t)(b * LL)) * HH + n * HDIM + d;
    for (int k = kg; k <= kmax; k += 8) {
        float v = vb[(size_t)k * HH];
        a0 += Ssc[0 * SSP + k] * v;
        a1 += Ssc[1 * SSP + k] * v;
        a2 += Ssc[2 * SSP + k] * v;
        a3 += Ssc[3 * SSP + k] * v;
    }
    const float* tvb = timeV + n * HDIM + d;
    for (int t = kg; t < NT; t += 8) {
        float v = tvb[(size_t)t * HH];
        a0 += WB[0 * NT + t] * v;
        a1 += WB[1 * NT + t] * v;
        a2 += WB[2 * NT + t] * v;
        a3 += WB[3 * NT + t] * v;
    }
    atomicAdd(&Ost[0 * HDIM + d], a0);
    atomicAdd(&Ost[1 * HDIM + d], a1);
    atomicAdd(&Ost[2 * HDIM + d], a2);
    atomicAdd(&Ost[3 * HDIM + d], a3);
    __syncthreads();
    if (tid < 128) {
        int qi = tid >> 5, dd = tid & 31;
        att[((size_t)(b * LL + q0 + qi)) * HH + n * HDIM + dd] = Ost[tid];
    }
}

// ===== fused FFN (+last-LN+logits): M=4 rows, N=128, 256 threads ===========
__global__ void k_ffn(const float* __restrict__ Qin, const float* __restrict__ att,
                      const float* __restrict__ g, const float* __restrict__ bia,
                      const float* __restrict__ W1, const float* __restrict__ b1,
                      const float* __restrict__ W2, const float* __restrict__ b2,
                      const int* __restrict__ log_seqs,
                      const float* __restrict__ lg, const float* __restrict__ lb,
                      const float* __restrict__ item_emb,
                      const int* __restrict__ pos, const int* __restrict__ neg,
                      float* __restrict__ out, float* __restrict__ logits, int last) {
    int row0 = blockIdx.x * 4;
    int tid = threadIdx.x;
    int wv = tid >> 6, ln = tid & 63;
    __shared__ float As[4 * FSP];     // y = LN(Qin+att), later out
    __shared__ float H1[4 * FSP];
    __shared__ float Bs[128 * BSP];   // 64-col W chunk, transposed

    {   // per-row LN (wave wv owns row wv)
        int row = row0 + wv;
        float v0 = Qin[(size_t)row * HH + ln]      + att[(size_t)row * HH + ln];
        float v1 = Qin[(size_t)row * HH + ln + 64] + att[(size_t)row * HH + ln + 64];
        float s = v0 + v1, s2 = v0 * v0 + v1 * v1;
        for (int off = 32; off; off >>= 1) {
            s  += __shfl_xor(s, off);
            s2 += __shfl_xor(s2, off);
        }
        float mean = s * (1.f / HH);
        float var  = s2 * (1.f / HH) - mean * mean;
        float inv  = 1.f / sqrtf(var + 1e-8f);
        As[wv * FSP + ln]      = (v0 - mean) * inv * g[ln]      + bia[ln];
        As[wv * FSP + ln + 64] = (v1 - mean) * inv * g[ln + 64] + bia[ln + 64];
    }
    __syncthreads();

    int jx = ln;
    // ---- FF1 ----
    for (int c = 0; c < 2; c++) {
        int k4 = tid & 31, jj0 = tid >> 5;
        #pragma unroll
        for (int p = 0; p < 8; p++) {
            int jj = jj0 + p * 8;
            float4 w = *(const float4*)(W1 + (size_t)(c * 64 + jj) * HH + k4 * 4);
            Bs[(k4 * 4 + 0) * BSP + jj] = w.x;
            Bs[(k4 * 4 + 1) * BSP + jj] = w.y;
            Bs[(k4 * 4 + 2) * BSP + jj] = w.z;
            Bs[(k4 * 4 + 3) * BSP + jj] = w.w;
        }
        __syncthreads();
        float acc = 0.f;
        #pragma unroll 8
        for (int k = 0; k < HH; k++)
            acc += As[wv * FSP + k] * Bs[k * BSP + jx];
        int col = c * 64 + jx;
        float t = acc + b1[col];
        H1[wv * FSP + col] = t > 0.f ? t : 0.f;
        __syncthreads();
    }

    // ---- FF2 ----
    int rowm = row0 + wv;
    int keepz = (log_seqs[rowm] == 0);
    for (int c = 0; c < 2; c++) {
        int k4 = tid & 31, jj0 = tid >> 5;
        #pragma unroll
        for (int p = 0; p < 8; p++) {
            int jj = jj0 + p * 8;
            float4 w = *(const float4*)(W2 + (size_t)(c * 64 + jj) * HH + k4 * 4);
            Bs[(k4 * 4 + 0) * BSP + jj] = w.x;
            Bs[(k4 * 4 + 1) * BSP + jj] = w.y;
            Bs[(k4 * 4 + 2) * BSP + jj] = w.z;
            Bs[(k4 * 4 + 3) * BSP + jj] = w.w;
        }
        __syncthreads();
        float acc = 0.f;
        #pragma unroll 8
        for (int k = 0; k < HH; k++)
            acc += H1[wv * FSP + k] * Bs[k * BSP + jx];
        int col = c * 64 + jx;
        float o = acc + b2[col] + As[wv * FSP + col];
        if (keepz) o = 0.f;
        if (!last) out[(size_t)rowm * HH + col] = o;
        As[wv * FSP + col] = o;
        __syncthreads();
    }

    // ---- last layer: LN + pos/neg logits ----
    if (last) {
        float o0 = As[wv * FSP + ln], o1 = As[wv * FSP + ln + 64];
        float s = o0 + o1, s2 = o0 * o0 + o1 * o1;
        for (int off = 32; off; off >>= 1) {
            s  += __shfl_xor(s, off);
            s2 += __shfl_xor(s2, off);
        }
        float mean = s * (1.f / HH);
        float var  = s2 * (1.f / HH) - mean * mean;
        float inv  = 1.f / sqrtf(var + 1e-8f);
        float f0 = (o0 - mean) * inv * lg[ln]      + lb[ln];
        float f1 = (o1 - mean) * inv * lg[ln + 64] + lb[ln + 64];
        int ip = pos[rowm], in_ = neg[rowm];
        float vp = f0 * item_emb[(size_t)ip * HH + ln] + f1 * item_emb[(size_t)ip * HH + ln + 64];
        float vn = f0 * item_emb[(size_t)in_ * HH + ln] + f1 * item_emb[(size_t)in_ * HH + ln + 64];
        for (int off = 32; off; off >>= 1) {
            vp += __shfl_xor(vp, off);
            vn += __shfl_xor(vn, off);
        }
        if (ln == 0) {
            logits[rowm]      = vp;
            logits[BL + rowm] = vn;
        }
    }
}

extern "C" void kernel_launch(void* const* d_in, const int* in_sizes, int n_in,
                              void* d_out, int out_size, void* d_ws, size_t ws_size,
                              hipStream_t stream) {
    const int* log_seqs   = (const int*)d_in[1];
    const int* tm         = (const int*)d_in[2];
    const int* pos_seqs   = (const int*)d_in[3];
    const int* neg_seqs   = (const int*)d_in[4];
    const float* item_emb = (const float*)d_in[5];
    const float* posK     = (const float*)d_in[6];
    const float* posV     = (const float*)d_in[7];
    const float* timeK    = (const float*)d_in[8];
    const float* timeV    = (const float*)d_in[9];
    const float* attn_g   = (const float*)d_in[10];
    const float* attn_b   = (const float*)d_in[11];
    const float* Wq       = (const float*)d_in[12];
    const float* bq       = (const float*)d_in[13];
    const float* Wk       = (const float*)d_in[14];
    const float* bk       = (const float*)d_in[15];
    const float* Wv       = (const float*)d_in[16];
    const float* bv       = (const float*)d_in[17];
    const float* fwd_g    = (const float*)d_in[18];
    const float* fwd_b    = (const float*)d_in[19];
    const float* W1       = (const float*)d_in[20];
    const float* b1       = (const float*)d_in[21];
    const float* W2       = (const float*)d_in[22];
    const float* b2       = (const float*)d_in[23];
    const float* last_g   = (const float*)d_in[24];
    const float* last_b   = (const float*)d_in[25];

    float* seqs = (float*)d_ws;            // 6 x B*L*H f32 = ~4.9 MB
    float* Qin  = seqs + (size_t)BL * HH;
    float* Qb   = Qin  + (size_t)BL * HH;
    float* Kb   = Qb   + (size_t)BL * HH;
    float* Vb   = Kb   + (size_t)BL * HH;
    float* att  = Vb   + (size_t)BL * HH;

    for (int i = 0; i < NBLK; i++) {
        k_qkv_gemm<<<300, 256, 0, stream>>>(i == 0 ? nullptr : seqs, log_seqs, item_emb,
                                            attn_g + i * HH, attn_b + i * HH,
                                            Wq + (size_t)i * HH * HH, bq + i * HH,
                                            Wk + (size_t)i * HH * HH, bk + i * HH,
                                            Wv + (size_t)i * HH * HH, bv + i * HH,
                                            posK, posV, Qin, Qb, Kb, Vb);
        k_attn<<<NQT4 * 32, 256, 0, stream>>>(Qb, Kb, Vb, timeK, timeV, tm, att);
        k_ffn<<<BL / 4, 256, 0, stream>>>(Qin, att, fwd_g + i * HH, fwd_b + i * HH,
                                          W1 + (size_t)i * HH * HH, b1 + i * HH,
                                          W2 + (size_t)i * HH * HH, b2 + i * HH,
                                          log_seqs, last_g, last_b, item_emb,
                                          pos_seqs, neg_seqs,
                                          seqs, (float*)d_out, (i == NBLK - 1) ? 1 : 0);
    }
}

// Round 10
// 238.425 us; speedup vs baseline: 1.0829x; 1.0470x over previous
//
#include <hip/hip_runtime.h>
#include <hip/hip_bf16.h>

#define BB 8
#define LL 200
#define HH 128
#define NHEAD 4
#define HDIM 32
#define NBLK 2
#define BL (BB * LL)
#define NT 257            // TIME_SPAN+1
#define QT 8              // attn queries per tile
#define NQT 25            // 200/8
#define SSP 208           // attn score row stride
#define KTP 66            // attn KstT row stride
#define TSP 132           // GEMM tile row stride [r][k]

static constexpr float SQRT_H    = 11.313708498984761f;   // sqrt(128)
static constexpr float INV_SCALE = 0.17677669529663687f;  // 1/sqrt(32)
static constexpr float PADV      = -4294967295.0f;        // -2^32+1

// ===== QKV GEMM: 32x16 tiles, 50 Mt x 24 Nt = 1200 blocks, 256 thr ========
// nt 0-7 -> Q (A=LN(x), *INV_SCALE), 8-15 -> K (+posK), 16-23 -> V (+posV)
__global__ void k_qkv_gemm(const float* __restrict__ seqs_in,
                           const int* __restrict__ log_seqs,
                           const float* __restrict__ item_emb,
                           const float* __restrict__ g, const float* __restrict__ bia,
                           const float* __restrict__ Wq, const float* __restrict__ bq,
                           const float* __restrict__ Wk, const float* __restrict__ bk,
                           const float* __restrict__ Wv, const float* __restrict__ bv,
                           const float* __restrict__ posK, const float* __restrict__ posV,
                           float* __restrict__ Qin, float* __restrict__ Q,
                           float* __restrict__ K, float* __restrict__ V) {
    int mt = blockIdx.x / 24, nt = blockIdx.x % 24;
    int matsel = nt >> 3;              // 0=Q 1=K 2=V
    int jb = (nt & 7) * 16;
    int row0 = mt * 32;
    int tid = threadIdx.x;
    __shared__ float As[32 * TSP];     // 16.9 KB [m][k]
    __shared__ float Bs[16 * TSP];     //  8.4 KB [j][k]

    {   // stage A: 32 rows x 128, 8 threads/row; LN for Q-tiles
        int r = tid >> 3, seg = tid & 7;
        int row = row0 + r;
        float4 vv[4];
        if (seqs_in) {
            #pragma unroll
            for (int i = 0; i < 4; i++)
                vv[i] = *(const float4*)(seqs_in + (size_t)row * HH + seg * 16 + i * 4);
        } else {
            int idx = log_seqs[row];
            if (idx == 0) {
                #pragma unroll
                for (int i = 0; i < 4; i++) vv[i] = make_float4(0.f, 0.f, 0.f, 0.f);
            } else {
                #pragma unroll
                for (int i = 0; i < 4; i++) {
                    float4 e = *(const float4*)(item_emb + (size_t)idx * HH + seg * 16 + i * 4);
                    vv[i] = make_float4(e.x * SQRT_H, e.y * SQRT_H, e.z * SQRT_H, e.w * SQRT_H);
                }
            }
        }
        if (matsel == 0) {
            float s = 0.f, s2 = 0.f;
            #pragma unroll
            for (int i = 0; i < 4; i++) {
                s  += vv[i].x + vv[i].y + vv[i].z + vv[i].w;
                s2 += vv[i].x * vv[i].x + vv[i].y * vv[i].y + vv[i].z * vv[i].z + vv[i].w * vv[i].w;
            }
            #pragma unroll
            for (int off = 1; off < 8; off <<= 1) {
                s  += __shfl_xor(s, off);
                s2 += __shfl_xor(s2, off);
            }
            float mean = s * (1.f / HH);
            float var  = s2 * (1.f / HH) - mean * mean;
            float inv  = 1.f / sqrtf(var + 1e-8f);
            #pragma unroll
            for (int i = 0; i < 4; i++) {
                int k = seg * 16 + i * 4;
                float4 g4 = *(const float4*)(g + k);
                float4 b4 = *(const float4*)(bia + k);
                float4 y;
                y.x = (vv[i].x - mean) * inv * g4.x + b4.x;
                y.y = (vv[i].y - mean) * inv * g4.y + b4.y;
                y.z = (vv[i].z - mean) * inv * g4.z + b4.z;
                y.w = (vv[i].w - mean) * inv * g4.w + b4.w;
                *(float4*)&As[r * TSP + k] = y;
                if (nt == 0) *(float4*)(Qin + (size_t)row * HH + k) = y;
            }
        } else {
            #pragma unroll
            for (int i = 0; i < 4; i++)
                *(float4*)&As[r * TSP + seg * 16 + i * 4] = vv[i];
        }
    }
    {   // stage B: 16 W-rows x 128 k
        const float* W = (matsel == 0) ? Wq : (matsel == 1) ? Wk : Wv;
        int j = tid >> 4, seg = tid & 15;
        float4 w = *(const float4*)(W + (size_t)(jb + j) * HH + seg * 8);
        float4 w2 = *(const float4*)(W + (size_t)(jb + j) * HH + seg * 8 + 4);
        *(float4*)&Bs[j * TSP + seg * 8] = w;
        *(float4*)&Bs[j * TSP + seg * 8 + 4] = w2;
    }
    __syncthreads();

    int m = tid >> 3, jg = tid & 7;    // 2 output cols per thread
    float acc0 = 0.f, acc1 = 0.f;
    const float* ar = &As[m * TSP];
    const float* b0r = &Bs[(jg * 2) * TSP];
    const float* b1r = &Bs[(jg * 2 + 1) * TSP];
    #pragma unroll 4
    for (int k4 = 0; k4 < 32; k4++) {
        float4 a = *(const float4*)(ar + k4 * 4);
        float4 b0 = *(const float4*)(b0r + k4 * 4);
        float4 b1 = *(const float4*)(b1r + k4 * 4);
        acc0 += a.x * b0.x + a.y * b0.y + a.z * b0.z + a.w * b0.w;
        acc1 += a.x * b1.x + a.y * b1.y + a.z * b1.z + a.w * b1.w;
    }
    int row = row0 + m;
    int col = jb + jg * 2;
    int l = row % LL;
    if (matsel == 0) {
        float2 bb = *(const float2*)(bq + col);
        *(float2*)(Q + (size_t)row * HH + col) =
            make_float2((acc0 + bb.x) * INV_SCALE, (acc1 + bb.y) * INV_SCALE);
    } else if (matsel == 1) {
        float2 bb = *(const float2*)(bk + col);
        float2 pk = *(const float2*)(posK + (size_t)l * HH + col);
        *(float2*)(K + (size_t)row * HH + col) =
            make_float2(acc0 + bb.x + pk.x, acc1 + bb.y + pk.y);
    } else {
        float2 bb = *(const float2*)(bv + col);
        float2 pv = *(const float2*)(posV + (size_t)l * HH + col);
        *(float2*)(V + (size_t)row * HH + col) =
            make_float2(acc0 + bb.x + pv.x, acc1 + bb.y + pv.y);
    }
}

// ===== attention (R7-verified): block = (b, head, 8-q tile), 256 thr ======
__global__ void k_attn(const float* __restrict__ Q, const float* __restrict__ K,
                       const float* __restrict__ V,
                       const float* __restrict__ timeK, const float* __restrict__ timeV,
                       const int* __restrict__ tm,
                       float* __restrict__ att) {
    int bn = blockIdx.x & 31;
    int b = bn >> 2, n = bn & 3;
    int qt = (NQT - 1) - (blockIdx.x >> 5);   // heavy tiles first
    int q0 = qt * QT;
    int kmax = q0 + QT - 1;
    int tid = threadIdx.x;
    int wv = tid >> 6, ln = tid & 63;

    __shared__ float Qs[QT * HDIM];
    __shared__ float KstT[HDIM * KTP];
    __shared__ float DTW[QT * NT];
    __shared__ float Ssc[QT * SSP];
    __shared__ int   tmst[QT * LL];
    __shared__ float Ost[QT * HDIM];

    Ost[tid] = 0.f;
    if (tid < 64) {
        int qi = tid >> 3, d4 = tid & 7;
        *(float4*)(Qs + qi * HDIM + d4 * 4) =
            *(const float4*)(Q + ((size_t)(b * LL + q0 + qi)) * HH + n * HDIM + d4 * 4);
    }
    #pragma unroll
    for (int qi = 0; qi < QT; qi++)
        if (tid < LL)
            tmst[qi * LL + tid] = tm[((size_t)(b * LL + q0 + qi)) * LL + tid];
    __syncthreads();

    int k2 = tid & 31, qi_c = tid >> 5;

    // DT[qi][tau] = Qh . timeKh[tau]
    for (int c = 0; c < 5; c++) {
        #pragma unroll
        for (int p = 0; p < 2; p++) {
            int idx = tid + p * 256;
            int r = idx >> 3, d4 = idx & 7;
            int tau = c * 64 + r;
            float4 w = make_float4(0.f, 0.f, 0.f, 0.f);
            if (tau < NT) w = *(const float4*)(timeK + (size_t)tau * HH + n * HDIM + d4 * 4);
            KstT[(d4 * 4 + 0) * KTP + r] = w.x;
            KstT[(d4 * 4 + 1) * KTP + r] = w.y;
            KstT[(d4 * 4 + 2) * KTP + r] = w.z;
            KstT[(d4 * 4 + 3) * KTP + r] = w.w;
        }
        __syncthreads();
        float a0 = 0.f, a1 = 0.f;
        #pragma unroll 4
        for (int d = 0; d < HDIM; d++) {
            float qv = Qs[qi_c * HDIM + d];
            float2 kv = *(const float2*)&KstT[d * KTP + k2 * 2];
            a0 += qv * kv.x; a1 += qv * kv.y;
        }
        int tau0 = c * 64 + k2 * 2;
        if (tau0 < NT)     DTW[qi_c * NT + tau0]     = a0;
        if (tau0 + 1 < NT) DTW[qi_c * NT + tau0 + 1] = a1;
        __syncthreads();
    }

    // S[qi][k] = Qh.Kh[k] + DT[qi][tm[k]], causal
    int nch = (kmax >> 6) + 1;
    for (int c = 0; c < nch; c++) {
        #pragma unroll
        for (int p = 0; p < 2; p++) {
            int idx = tid + p * 256;
            int r = idx >> 3, d4 = idx & 7;
            int k = c * 64 + r;
            float4 w = make_float4(0.f, 0.f, 0.f, 0.f);
            if (k < LL) w = *(const float4*)(K + ((size_t)(b * LL + k)) * HH + n * HDIM + d4 * 4);
            KstT[(d4 * 4 + 0) * KTP + r] = w.x;
            KstT[(d4 * 4 + 1) * KTP + r] = w.y;
            KstT[(d4 * 4 + 2) * KTP + r] = w.z;
            KstT[(d4 * 4 + 3) * KTP + r] = w.w;
        }
        __syncthreads();
        float a0 = 0.f, a1 = 0.f;
        #pragma unroll 4
        for (int d = 0; d < HDIM; d++) {
            float qv = Qs[qi_c * HDIM + d];
            float2 kv = *(const float2*)&KstT[d * KTP + k2 * 2];
            a0 += qv * kv.x; a1 += qv * kv.y;
        }
        int q = q0 + qi_c;
        int k0 = c * 64 + k2 * 2;
        if (k0 <= kmax)
            Ssc[qi_c * SSP + k0] = (k0 <= q) ? (a0 + DTW[qi_c * NT + tmst[qi_c * LL + k0]]) : PADV;
        if (k0 + 1 <= kmax)
            Ssc[qi_c * SSP + k0 + 1] = (k0 + 1 <= q) ? (a1 + DTW[qi_c * NT + tmst[qi_c * LL + k0 + 1]]) : PADV;
        __syncthreads();
    }

    for (int idx = tid; idx < QT * NT; idx += 256) DTW[idx] = 0.f;
    __syncthreads();

    // softmax + scatter W (DTW reused as bins)
    for (int rr = 0; rr < 2; rr++) {
        int qi = wv + rr * 4;
        int q = q0 + qi;
        float sv[4];
        float m = PADV;
        #pragma unroll
        for (int jj = 0; jj < 4; jj++) {
            int k = ln + 64 * jj;
            sv[jj] = (k <= q) ? Ssc[qi * SSP + k] : PADV;
            m = fmaxf(m, sv[jj]);
        }
        for (int off = 32; off; off >>= 1) m = fmaxf(m, __shfl_xor(m, off));
        float sum = 0.f;
        #pragma unroll
        for (int jj = 0; jj < 4; jj++) {
            int k = ln + 64 * jj;
            sv[jj] = (k <= q) ? __expf(sv[jj] - m) : 0.f;
            sum += sv[jj];
        }
        for (int off = 32; off; off >>= 1) sum += __shfl_xor(sum, off);
        float inv = 1.f / sum;
        #pragma unroll
        for (int jj = 0; jj < 4; jj++) {
            int k = ln + 64 * jj;
            float p = sv[jj] * inv;
            if (k < SSP) Ssc[qi * SSP + k] = (k <= q) ? p : 0.f;
            if (k <= q) atomicAdd(&DTW[qi * NT + tmst[qi * LL + k]], p);
        }
    }
    __syncthreads();

    // O = P@Vh + W@timeVh
    int d = tid & 31, kg = tid >> 5;
    float acc[QT] = {0,0,0,0,0,0,0,0};
    const float* vb = V + ((size_t)(b * LL)) * HH + n * HDIM + d;
    for (int k = kg; k <= kmax; k += 8) {
        float v = vb[(size_t)k * HH];
        #pragma unroll
        for (int qi = 0; qi < QT; qi++) acc[qi] += Ssc[qi * SSP + k] * v;
    }
    const float* tvb = timeV + n * HDIM + d;
    for (int t = kg; t < NT; t += 8) {
        float v = tvb[(size_t)t * HH];
        #pragma unroll
        for (int qi = 0; qi < QT; qi++) acc[qi] += DTW[qi * NT + t] * v;
    }
    #pragma unroll
    for (int qi = 0; qi < QT; qi++) atomicAdd(&Ost[qi * HDIM + d], acc[qi]);
    __syncthreads();
    {
        int qi = tid >> 5;
        att[((size_t)(b * LL + q0 + qi)) * HH + n * HDIM + (tid & 31)] = Ost[tid];
    }
}

// ===== FF1: h1 = relu(LN(Qin+att)@W1^T + b1), 16x16 tiles, 800 blocks =====
__global__ void k_ff1(const float* __restrict__ Qin, const float* __restrict__ att,
                      const float* __restrict__ g, const float* __restrict__ bia,
                      const float* __restrict__ W1, const float* __restrict__ b1,
                      float* __restrict__ h1) {
    int mt = blockIdx.x >> 3, jb = (blockIdx.x & 7) * 16;
    int row0 = mt * 16;
    int tid = threadIdx.x;
    __shared__ float As[16 * TSP];
    __shared__ float Bs[16 * TSP];

    {   // stage A = LN(Qin+att), 16 threads/row
        int r = tid >> 4, seg = tid & 15;
        int row = row0 + r;
        float4 vv[2];
        #pragma unroll
        for (int i = 0; i < 2; i++) {
            int k = seg * 8 + i * 4;
            float4 q4 = *(const float4*)(Qin + (size_t)row * HH + k);
            float4 a4 = *(const float4*)(att + (size_t)row * HH + k);
            vv[i] = make_float4(q4.x + a4.x, q4.y + a4.y, q4.z + a4.z, q4.w + a4.w);
        }
        float s = 0.f, s2 = 0.f;
        #pragma unroll
        for (int i = 0; i < 2; i++) {
            s  += vv[i].x + vv[i].y + vv[i].z + vv[i].w;
            s2 += vv[i].x * vv[i].x + vv[i].y * vv[i].y + vv[i].z * vv[i].z + vv[i].w * vv[i].w;
        }
        #pragma unroll
        for (int off = 1; off < 16; off <<= 1) {
            s  += __shfl_xor(s, off);
            s2 += __shfl_xor(s2, off);
        }
        float mean = s * (1.f / HH);
        float var  = s2 * (1.f / HH) - mean * mean;
        float inv  = 1.f / sqrtf(var + 1e-8f);
        #pragma unroll
        for (int i = 0; i < 2; i++) {
            int k = seg * 8 + i * 4;
            float4 g4 = *(const float4*)(g + k);
            float4 b4 = *(const float4*)(bia + k);
            float4 y;
            y.x = (vv[i].x - mean) * inv * g4.x + b4.x;
            y.y = (vv[i].y - mean) * inv * g4.y + b4.y;
            y.z = (vv[i].z - mean) * inv * g4.z + b4.z;
            y.w = (vv[i].w - mean) * inv * g4.w + b4.w;
            *(float4*)&As[r * TSP + k] = y;
        }
    }
    {   // stage B
        int j = tid >> 4, seg = tid & 15;
        *(float4*)&Bs[j * TSP + seg * 8]     = *(const float4*)(W1 + (size_t)(jb + j) * HH + seg * 8);
        *(float4*)&Bs[j * TSP + seg * 8 + 4] = *(const float4*)(W1 + (size_t)(jb + j) * HH + seg * 8 + 4);
    }
    __syncthreads();

    int m = tid >> 4, j = tid & 15;
    float acc = 0.f;
    const float* ar = &As[m * TSP];
    const float* br = &Bs[j * TSP];
    #pragma unroll 4
    for (int k4 = 0; k4 < 32; k4++) {
        float4 a = *(const float4*)(ar + k4 * 4);
        float4 b = *(const float4*)(br + k4 * 4);
        acc += a.x * b.x + a.y * b.y + a.z * b.z + a.w * b.w;
    }
    int col = jb + j;
    float t = acc + b1[col];
    h1[(size_t)(row0 + m) * HH + col] = t > 0.f ? t : 0.f;
}

// ===== FF2: out = (h1@W2^T + b2 + LN(Qin+att))*keep, 16x16, 800 blocks ====
__global__ void k_ff2(const float* __restrict__ h1,
                      const float* __restrict__ Qin, const float* __restrict__ att,
                      const float* __restrict__ g, const float* __restrict__ bia,
                      const float* __restrict__ W2, const float* __restrict__ b2,
                      const int* __restrict__ log_seqs,
                      float* __restrict__ out) {
    int mt = blockIdx.x >> 3, jb = (blockIdx.x & 7) * 16;
    int row0 = mt * 16;
    int tid = threadIdx.x;
    __shared__ float As[16 * TSP];
    __shared__ float Bs[16 * TSP];
    __shared__ float mu[16], rstd[16];

    {   // stage A = h1; compute residual row stats
        int r = tid >> 4, seg = tid & 15;
        int row = row0 + r;
        #pragma unroll
        for (int i = 0; i < 2; i++) {
            int k = seg * 8 + i * 4;
            *(float4*)&As[r * TSP + k] = *(const float4*)(h1 + (size_t)row * HH + k);
        }
        float s = 0.f, s2 = 0.f;
        #pragma unroll
        for (int i = 0; i < 2; i++) {
            int k = seg * 8 + i * 4;
            float4 q4 = *(const float4*)(Qin + (size_t)row * HH + k);
            float4 a4 = *(const float4*)(att + (size_t)row * HH + k);
            float4 v = make_float4(q4.x + a4.x, q4.y + a4.y, q4.z + a4.z, q4.w + a4.w);
            s  += v.x + v.y + v.z + v.w;
            s2 += v.x * v.x + v.y * v.y + v.z * v.z + v.w * v.w;
        }
        #pragma unroll
        for (int off = 1; off < 16; off <<= 1) {
            s  += __shfl_xor(s, off);
            s2 += __shfl_xor(s2, off);
        }
        float mean = s * (1.f / HH);
        float var  = s2 * (1.f / HH) - mean * mean;
        if (seg == 0) { mu[r] = mean; rstd[r] = 1.f / sqrtf(var + 1e-8f); }
    }
    {   // stage B
        int j = tid >> 4, seg = tid & 15;
        *(float4*)&Bs[j * TSP + seg * 8]     = *(const float4*)(W2 + (size_t)(jb + j) * HH + seg * 8);
        *(float4*)&Bs[j * TSP + seg * 8 + 4] = *(const float4*)(W2 + (size_t)(jb + j) * HH + seg * 8 + 4);
    }
    __syncthreads();

    int m = tid >> 4, j = tid & 15;
    float acc = 0.f;
    const float* ar = &As[m * TSP];
    const float* br = &Bs[j * TSP];
    #pragma unroll 4
    for (int k4 = 0; k4 < 32; k4++) {
        float4 a = *(const float4*)(ar + k4 * 4);
        float4 b = *(const float4*)(br + k4 * 4);
        acc += a.x * b.x + a.y * b.y + a.z * b.z + a.w * b.w;
    }
    int row = row0 + m;
    int col = jb + j;
    float resid = Qin[(size_t)row * HH + col] + att[(size_t)row * HH + col];
    float y = (resid - mu[m]) * rstd[m] * g[col] + bia[col];
    float o = acc + b2[col] + y;
    if (log_seqs[row] == 0) o = 0.f;
    out[(size_t)row * HH + col] = o;
}

// ===== fused last-LN + pos/neg logits: one block per row ==================
__global__ void k_lnlogits(const float* __restrict__ seqs,
                           const float* __restrict__ g, const float* __restrict__ bia,
                           const float* __restrict__ item_emb,
                           const int* __restrict__ pos, const int* __restrict__ neg,
                           float* __restrict__ out) {
    int row = blockIdx.x;
    int h = threadIdx.x;
    float v = seqs[(size_t)row * HH + h];
    float s = v, s2 = v * v;
    for (int off = 32; off; off >>= 1) {
        s  += __shfl_xor(s, off);
        s2 += __shfl_xor(s2, off);
    }
    __shared__ float r1[2], r2[2];
    if ((h & 63) == 0) { r1[h >> 6] = s; r2[h >> 6] = s2; }
    __syncthreads();
    float mean = (r1[0] + r1[1]) * (1.f / HH);
    float var  = (r2[0] + r2[1]) * (1.f / HH) - mean * mean;
    float inv = 1.f / sqrtf(var + 1e-8f);
    float f = (v - mean) * inv * g[h] + bia[h];

    int ip = pos[row], in_ = neg[row];
    float vp = f * item_emb[(size_t)ip * HH + h];
    float vn = f * item_emb[(size_t)in_ * HH + h];
    for (int off = 32; off; off >>= 1) {
        vp += __shfl_xor(vp, off);
        vn += __shfl_xor(vn, off);
    }
    __shared__ float rp[2], rn[2];
    if ((h & 63) == 0) { rp[h >> 6] = vp; rn[h >> 6] = vn; }
    __syncthreads();
    if (h == 0) {
        out[row]      = rp[0] + rp[1];
        out[BL + row] = rn[0] + rn[1];
    }
}

extern "C" void kernel_launch(void* const* d_in, const int* in_sizes, int n_in,
                              void* d_out, int out_size, void* d_ws, size_t ws_size,
                              hipStream_t stream) {
    const int* log_seqs   = (const int*)d_in[1];
    const int* tm         = (const int*)d_in[2];
    const int* pos_seqs   = (const int*)d_in[3];
    const int* neg_seqs   = (const int*)d_in[4];
    const float* item_emb = (const float*)d_in[5];
    const float* posK     = (const float*)d_in[6];
    const float* posV     = (const float*)d_in[7];
    const float* timeK    = (const float*)d_in[8];
    const float* timeV    = (const float*)d_in[9];
    const float* attn_g   = (const float*)d_in[10];
    const float* attn_b   = (const float*)d_in[11];
    const float* Wq       = (const float*)d_in[12];
    const float* bq       = (const float*)d_in[13];
    const float* Wk       = (const float*)d_in[14];
    const float* bk       = (const float*)d_in[15];
    const float* Wv       = (const float*)d_in[16];
    const float* bv       = (const float*)d_in[17];
    const float* fwd_g    = (const float*)d_in[18];
    const float* fwd_b    = (const float*)d_in[19];
    const float* W1       = (const float*)d_in[20];
    const float* b1       = (const float*)d_in[21];
    const float* W2       = (const float*)d_in[22];
    const float* b2       = (const float*)d_in[23];
    const float* last_g   = (const float*)d_in[24];
    const float* last_b   = (const float*)d_in[25];

    float* seqs = (float*)d_ws;            // 7 x B*L*H f32 = ~5.7 MB
    float* Qin  = seqs + (size_t)BL * HH;
    float* Qb   = Qin  + (size_t)BL * HH;
    float* Kb   = Qb   + (size_t)BL * HH;
    float* Vb   = Kb   + (size_t)BL * HH;
    float* att  = Vb   + (size_t)BL * HH;
    float* h1   = att  + (size_t)BL * HH;

    for (int i = 0; i < NBLK; i++) {
        k_qkv_gemm<<<1200, 256, 0, stream>>>(i == 0 ? nullptr : seqs, log_seqs, item_emb,
                                             attn_g + i * HH, attn_b + i * HH,
                                             Wq + (size_t)i * HH * HH, bq + i * HH,
                                             Wk + (size_t)i * HH * HH, bk + i * HH,
                                             Wv + (size_t)i * HH * HH, bv + i * HH,
                                             posK, posV, Qin, Qb, Kb, Vb);
        k_attn<<<NQT * 32, 256, 0, stream>>>(Qb, Kb, Vb, timeK, timeV, tm, att);
        k_ff1<<<800, 256, 0, stream>>>(Qin, att, fwd_g + i * HH, fwd_b + i * HH,
                                       W1 + (size_t)i * HH * HH, b1 + i * HH, h1);
        k_ff2<<<800, 256, 0, stream>>>(h1, Qin, att, fwd_g + i * HH, fwd_b + i * HH,
                                       W2 + (size_t)i * HH * HH, b2 + i * HH,
                                       log_seqs, seqs);
    }
    k_lnlogits<<<BL, HH, 0, stream>>>(seqs, last_g, last_b, item_emb,
                                      pos_seqs, neg_seqs, (float*)d_out);
}